// Round 1
// baseline (199.754 us; speedup 1.0000x reference)
//
#include <hip/hip_runtime.h>

typedef _Float16 f16x8 __attribute__((ext_vector_type(8)));
typedef float f32x4 __attribute__((ext_vector_type(4)));

#define NH 12
#define SEQ 2048
#define DM 768
#define DH 64

// ---------------- cast fp32 -> fp16 (X and the 4 weight matrices) --------
__global__ __launch_bounds__(256) void cast_kernel(
    const float* __restrict__ X, const float* __restrict__ Wq,
    const float* __restrict__ Wk, const float* __restrict__ Wv,
    const float* __restrict__ Wo, _Float16* __restrict__ Xh,
    _Float16* __restrict__ Wall)
{
    size_t base = ((size_t)blockIdx.x * 256 + threadIdx.x) * 8;
    const size_t NX = 3145728, NW = 589824, TOT = NX + 4 * NW;
    if (base >= TOT) return;
    const float* src;
    _Float16* dst;
    if (base < NX) { src = X + base; dst = Xh + base; }
    else {
        size_t r = base - NX;
        int w = (int)(r / NW);
        size_t o = r - (size_t)w * NW;
        src = (w == 0 ? Wq : w == 1 ? Wk : w == 2 ? Wv : Wo) + o;
        dst = Wall + r;
    }
    float4 a = *reinterpret_cast<const float4*>(src);
    float4 b = *reinterpret_cast<const float4*>(src + 4);
    f16x8 h;
    h[0] = (_Float16)a.x; h[1] = (_Float16)a.y; h[2] = (_Float16)a.z; h[3] = (_Float16)a.w;
    h[4] = (_Float16)b.x; h[5] = (_Float16)b.y; h[6] = (_Float16)b.z; h[7] = (_Float16)b.w;
    *reinterpret_cast<f16x8*>(dst) = h;
}

// ---------------- GEMM: out = A[4096x768] @ W^T + bias ------------------
// W is [N=768][K=768] row-major (i.e. B^T layout, K contiguous).
// mode is_out==0: write fp16 head-split Q/K/V (z selects Wq/Wk/Wv).
// mode is_out==1: write fp32 d_out + bias.
// 128x128 tile, BK=64, 4 waves in 2x2, each wave 64x64 = 4x4 16x16 frags.
__global__ __launch_bounds__(256) void gemm_kernel(
    const _Float16* __restrict__ A,
    const _Float16* __restrict__ Wbase,
    const float* __restrict__ b0, const float* __restrict__ b1,
    const float* __restrict__ b2,
    _Float16* __restrict__ outQKV, float* __restrict__ outF32, int is_out)
{
    __shared__ _Float16 Asm[128 * 64];
    __shared__ _Float16 Bsm[128 * 64];
    const int tid = threadIdx.x;
    const int m0 = blockIdx.x * 128, n0 = blockIdx.y * 128, z = blockIdx.z;
    const _Float16* Wp = Wbase + (size_t)z * 589824;
    const float* bias = (z == 0) ? b0 : (z == 1 ? b1 : b2);
    const int w = tid >> 6, lane = tid & 63, lr = lane & 15, lg = lane >> 4;
    const int wm = w >> 1, wn = w & 1;

    f32x4 acc[4][4] = {};
    for (int kt = 0; kt < 12; ++kt) {
        __syncthreads();
        // stage A tile [128][64] and B tile [128][64], XOR-swizzled (st_16x32 style)
        #pragma unroll
        for (int i = 0; i < 4; ++i) {
            int c = tid + i * 256;              // 0..1023 chunks of 8 elems
            int row = c >> 3, col = (c & 7) * 8;
            int sw = (row & 7) << 4;
            f16x8 av = *reinterpret_cast<const f16x8*>(A + (size_t)(m0 + row) * 768 + kt * 64 + col);
            *reinterpret_cast<f16x8*>((char*)Asm + ((row * 128 + col * 2) ^ sw)) = av;
            f16x8 bv = *reinterpret_cast<const f16x8*>(Wp + (size_t)(n0 + row) * 768 + kt * 64 + col);
            *reinterpret_cast<f16x8*>((char*)Bsm + ((row * 128 + col * 2) ^ sw)) = bv;
        }
        __syncthreads();
        #pragma unroll
        for (int kf = 0; kf < 2; ++kf) {
            f16x8 af[4], bf[4];
            #pragma unroll
            for (int mi = 0; mi < 4; ++mi) {
                int row = wm * 64 + mi * 16 + lr;
                af[mi] = *reinterpret_cast<const f16x8*>(
                    (char*)Asm + ((row * 128 + kf * 64 + lg * 16) ^ ((row & 7) << 4)));
            }
            #pragma unroll
            for (int nj = 0; nj < 4; ++nj) {
                int row = wn * 64 + nj * 16 + lr;
                bf[nj] = *reinterpret_cast<const f16x8*>(
                    (char*)Bsm + ((row * 128 + kf * 64 + lg * 16) ^ ((row & 7) << 4)));
            }
            #pragma unroll
            for (int mi = 0; mi < 4; ++mi)
                #pragma unroll
                for (int nj = 0; nj < 4; ++nj)
                    acc[mi][nj] = __builtin_amdgcn_mfma_f32_16x16x32_f16(
                        af[mi], bf[nj], acc[mi][nj], 0, 0, 0);
        }
    }
    // epilogue: C layout col = lane&15, row = (lane>>4)*4 + r
    #pragma unroll
    for (int mi = 0; mi < 4; ++mi) {
        #pragma unroll
        for (int nj = 0; nj < 4; ++nj) {
            #pragma unroll
            for (int r = 0; r < 4; ++r) {
                int gm = m0 + wm * 64 + mi * 16 + lg * 4 + r;
                int gn = n0 + wn * 64 + nj * 16 + lr;
                float v = acc[mi][nj][r] + bias[gn];
                if (!is_out) {
                    int bb = gm >> 11, s = gm & 2047, hh = gn >> 6, dd = gn & 63;
                    outQKV[(size_t)z * 3145728 +
                           ((((size_t)bb * NH + hh) * SEQ + s) * DH + dd)] = (_Float16)v;
                } else {
                    outF32[(size_t)gm * 768 + gn] = v;
                }
            }
        }
    }
}

// ---------------- flash attention: per (b, h, 64 q-rows) -----------------
// 4 waves; wave w owns q-rows [16w,16w+16). K-tile=64. Online softmax.
__global__ __launch_bounds__(256) void attn_kernel(
    const _Float16* __restrict__ Qh, const _Float16* __restrict__ Kh,
    const _Float16* __restrict__ Vh, const float* __restrict__ pb,
    const float* __restrict__ mask, _Float16* __restrict__ ctx)
{
    __shared__ _Float16 Kl[64 * 72];      // K tile [kt][d], padded stride 72
    __shared__ _Float16 Vt[64 * 72];      // V^T tile [d][kt], padded stride 72
    __shared__ _Float16 Pl[4 * 16 * 72];  // per-wave P tile [16 q][64 kt]
    const int tid = threadIdx.x, w = tid >> 6, lane = tid & 63;
    const int lr = lane & 15, lg = lane >> 4;
    const int q0 = blockIdx.x * 64, h = blockIdx.y, b = blockIdx.z;
    const size_t headoff = ((size_t)b * NH + h) * SEQ * DH;
    const _Float16* Qp = Qh + headoff;
    const _Float16* Kp = Kh + headoff;
    const _Float16* Vp = Vh + headoff;

    // Q A-frags: row = lane&15 within wave's 16 rows, k = 8*(lane>>4)+j
    f16x8 qf[2];
    #pragma unroll
    for (int kf = 0; kf < 2; ++kf)
        qf[kf] = *reinterpret_cast<const f16x8*>(
            Qp + (size_t)(q0 + w * 16 + lr) * DH + kf * 32 + lg * 8);

    f32x4 oacc[4] = {};
    float m_r[4], l_r[4];
    #pragma unroll
    for (int r = 0; r < 4; ++r) { m_r[r] = -3.0e38f; l_r[r] = 0.f; }
    _Float16* Pw = Pl + w * 16 * 72;

    for (int kt0 = 0; kt0 < SEQ; kt0 += 64) {
        __syncthreads();
        // stage K tile (linear) and V tile transposed; both tiles are
        // contiguous 8KB in global (full 64-elem rows).
        #pragma unroll
        for (int i = 0; i < 2; ++i) {
            int c = tid + i * 256;              // 0..511 chunks
            int row = c >> 3, col = (c & 7) * 8;
            f16x8 kv = *reinterpret_cast<const f16x8*>(Kp + (size_t)kt0 * DH + c * 8);
            *reinterpret_cast<f16x8*>(&Kl[row * 72 + col]) = kv;
            f16x8 vv = *reinterpret_cast<const f16x8*>(Vp + (size_t)kt0 * DH + c * 8);
            #pragma unroll
            for (int j = 0; j < 8; ++j) Vt[(col + j) * 72 + row] = vv[j];
        }
        __syncthreads();

        // scores: S = Q.K^T, 4 col-frags of 16 kt each
        f32x4 sc4[4] = {};
        #pragma unroll
        for (int cf = 0; cf < 4; ++cf) {
            #pragma unroll
            for (int kf = 0; kf < 2; ++kf) {
                f16x8 kb = *reinterpret_cast<const f16x8*>(
                    &Kl[(cf * 16 + lr) * 72 + kf * 32 + lg * 8]);
                sc4[cf] = __builtin_amdgcn_mfma_f32_16x16x32_f16(qf[kf], kb, sc4[cf], 0, 0, 0);
            }
        }
        // scale + position_bias + mask (fp32)
        float sv[4][4];
        #pragma unroll
        for (int cf = 0; cf < 4; ++cf) {
            int col = kt0 + cf * 16 + lr;
            float mk = mask[(size_t)b * SEQ + col];
            #pragma unroll
            for (int r = 0; r < 4; ++r) {
                int grow = q0 + w * 16 + lg * 4 + r;
                float pbv = pb[(size_t)h * SEQ * SEQ + (size_t)grow * SEQ + col];
                sv[cf][r] = sc4[cf][r] * 0.125f + pbv + mk;
            }
        }
        // online softmax: rows live in 16-lane groups (same lg)
        float tm[4], rs[4], scale[4];
        #pragma unroll
        for (int r = 0; r < 4; ++r) {
            float t = fmaxf(fmaxf(sv[0][r], sv[1][r]), fmaxf(sv[2][r], sv[3][r]));
            #pragma unroll
            for (int msk = 1; msk < 16; msk <<= 1) t = fmaxf(t, __shfl_xor(t, msk));
            float mn = fmaxf(m_r[r], t);
            scale[r] = __expf(m_r[r] - mn);
            m_r[r] = mn;
            rs[r] = 0.f;
        }
        #pragma unroll
        for (int cf = 0; cf < 4; ++cf)
            #pragma unroll
            for (int r = 0; r < 4; ++r) {
                float p = __expf(sv[cf][r] - m_r[r]);
                rs[r] += p;
                Pw[(lg * 4 + r) * 72 + cf * 16 + lr] = (_Float16)p;
            }
        #pragma unroll
        for (int r = 0; r < 4; ++r) {
            #pragma unroll
            for (int msk = 1; msk < 16; msk <<= 1) rs[r] += __shfl_xor(rs[r], msk);
            l_r[r] = l_r[r] * scale[r] + rs[r];
        }
        #pragma unroll
        for (int cf = 0; cf < 4; ++cf)
            #pragma unroll
            for (int r = 0; r < 4; ++r) oacc[cf][r] *= scale[r];

        // PV: A = P (from wave-private LDS), B = V (from transposed tile)
        #pragma unroll
        for (int kf = 0; kf < 2; ++kf) {
            f16x8 pa = *reinterpret_cast<const f16x8*>(&Pw[lr * 72 + kf * 32 + lg * 8]);
            #pragma unroll
            for (int cf = 0; cf < 4; ++cf) {
                f16x8 vb = *reinterpret_cast<const f16x8*>(
                    &Vt[(cf * 16 + lr) * 72 + kf * 32 + lg * 8]);
                oacc[cf] = __builtin_amdgcn_mfma_f32_16x16x32_f16(pa, vb, oacc[cf], 0, 0, 0);
            }
        }
    }
    // epilogue: ctx[b, s, h*64+d] fp16
    #pragma unroll
    for (int r = 0; r < 4; ++r) {
        float inv = 1.0f / l_r[r];
        int grow = q0 + w * 16 + lg * 4 + r;
        #pragma unroll
        for (int cf = 0; cf < 4; ++cf)
            ctx[((size_t)b * SEQ + grow) * DM + h * DH + cf * 16 + lr] =
                (_Float16)(oacc[cf][r] * inv);
    }
}

extern "C" void kernel_launch(void* const* d_in, const int* in_sizes, int n_in,
                              void* d_out, int out_size, void* d_ws, size_t ws_size,
                              hipStream_t stream) {
    const float* X    = (const float*)d_in[0];
    const float* mask = (const float*)d_in[1];
    const float* pb   = (const float*)d_in[2];
    const float* Wq   = (const float*)d_in[3];
    const float* bq   = (const float*)d_in[4];
    const float* Wk   = (const float*)d_in[5];
    const float* bk   = (const float*)d_in[6];
    const float* Wv   = (const float*)d_in[7];
    const float* bv   = (const float*)d_in[8];
    const float* Wo   = (const float*)d_in[9];
    const float* bo   = (const float*)d_in[10];
    float* out = (float*)d_out;

    _Float16* Xh   = (_Float16*)d_ws;            // 3145728
    _Float16* Wall = Xh + 3145728;               // 4 * 589824 (q,k,v,o)
    _Float16* QKV  = Wall + 4 * 589824;          // 3 * 3145728
    _Float16* ctx  = QKV + 3 * 3145728;          // 3145728

    cast_kernel<<<2688, 256, 0, stream>>>(X, Wq, Wk, Wv, Wo, Xh, Wall);
    gemm_kernel<<<dim3(32, 6, 3), 256, 0, stream>>>(
        Xh, Wall, bq, bk, bv, QKV, nullptr, 0);
    attn_kernel<<<dim3(32, 12, 2), 256, 0, stream>>>(
        QKV, QKV + 3145728, QKV + 2 * 3145728, pb, mask, ctx);
    gemm_kernel<<<dim3(32, 6, 1), 256, 0, stream>>>(
        ctx, Wall + 3 * 589824, bo, bo, bo, nullptr, out, 1);
}

// Round 2
// 192.072 us; speedup vs baseline: 1.0400x; 1.0400x over previous
//
#include <hip/hip_runtime.h>

typedef _Float16 f16x8 __attribute__((ext_vector_type(8)));
typedef float f32x4 __attribute__((ext_vector_type(4)));

#define NH 12
#define SEQ 2048
#define DM 768
#define DH 64

// ---------------- cast fp32 -> fp16 (X and the 4 weight matrices) --------
__global__ __launch_bounds__(256) void cast_kernel(
    const float* __restrict__ X, const float* __restrict__ Wq,
    const float* __restrict__ Wk, const float* __restrict__ Wv,
    const float* __restrict__ Wo, _Float16* __restrict__ Xh,
    _Float16* __restrict__ Wall)
{
    size_t base = ((size_t)blockIdx.x * 256 + threadIdx.x) * 8;
    const size_t NX = 3145728, NW = 589824, TOT = NX + 4 * NW;
    if (base >= TOT) return;
    const float* src;
    _Float16* dst;
    if (base < NX) { src = X + base; dst = Xh + base; }
    else {
        size_t r = base - NX;
        int w = (int)(r / NW);
        size_t o = r - (size_t)w * NW;
        src = (w == 0 ? Wq : w == 1 ? Wk : w == 2 ? Wv : Wo) + o;
        dst = Wall + r;
    }
    float4 a = *reinterpret_cast<const float4*>(src);
    float4 b = *reinterpret_cast<const float4*>(src + 4);
    f16x8 h;
    h[0] = (_Float16)a.x; h[1] = (_Float16)a.y; h[2] = (_Float16)a.z; h[3] = (_Float16)a.w;
    h[4] = (_Float16)b.x; h[5] = (_Float16)b.y; h[6] = (_Float16)b.z; h[7] = (_Float16)b.w;
    *reinterpret_cast<f16x8*>(dst) = h;
}

// ---------------- GEMM: out = A[4096x768] @ W^T + bias ------------------
__global__ __launch_bounds__(256) void gemm_kernel(
    const _Float16* __restrict__ A,
    const _Float16* __restrict__ Wbase,
    const float* __restrict__ b0, const float* __restrict__ b1,
    const float* __restrict__ b2,
    _Float16* __restrict__ outQKV, float* __restrict__ outF32, int is_out)
{
    __shared__ _Float16 Asm[128 * 64];
    __shared__ _Float16 Bsm[128 * 64];
    const int tid = threadIdx.x;
    const int m0 = blockIdx.x * 128, n0 = blockIdx.y * 128, z = blockIdx.z;
    const _Float16* Wp = Wbase + (size_t)z * 589824;
    const float* bias = (z == 0) ? b0 : (z == 1 ? b1 : b2);
    const int w = tid >> 6, lane = tid & 63, lr = lane & 15, lg = lane >> 4;
    const int wm = w >> 1, wn = w & 1;

    f32x4 acc[4][4] = {};
    for (int kt = 0; kt < 12; ++kt) {
        __syncthreads();
        #pragma unroll
        for (int i = 0; i < 4; ++i) {
            int c = tid + i * 256;
            int row = c >> 3, col = (c & 7) * 8;
            int sw = (row & 7) << 4;
            f16x8 av = *reinterpret_cast<const f16x8*>(A + (size_t)(m0 + row) * 768 + kt * 64 + col);
            *reinterpret_cast<f16x8*>((char*)Asm + ((row * 128 + col * 2) ^ sw)) = av;
            f16x8 bv = *reinterpret_cast<const f16x8*>(Wp + (size_t)(n0 + row) * 768 + kt * 64 + col);
            *reinterpret_cast<f16x8*>((char*)Bsm + ((row * 128 + col * 2) ^ sw)) = bv;
        }
        __syncthreads();
        #pragma unroll
        for (int kf = 0; kf < 2; ++kf) {
            f16x8 af[4], bf[4];
            #pragma unroll
            for (int mi = 0; mi < 4; ++mi) {
                int row = wm * 64 + mi * 16 + lr;
                af[mi] = *reinterpret_cast<const f16x8*>(
                    (char*)Asm + ((row * 128 + kf * 64 + lg * 16) ^ ((row & 7) << 4)));
            }
            #pragma unroll
            for (int nj = 0; nj < 4; ++nj) {
                int row = wn * 64 + nj * 16 + lr;
                bf[nj] = *reinterpret_cast<const f16x8*>(
                    (char*)Bsm + ((row * 128 + kf * 64 + lg * 16) ^ ((row & 7) << 4)));
            }
            #pragma unroll
            for (int mi = 0; mi < 4; ++mi)
                #pragma unroll
                for (int nj = 0; nj < 4; ++nj)
                    acc[mi][nj] = __builtin_amdgcn_mfma_f32_16x16x32_f16(
                        af[mi], bf[nj], acc[mi][nj], 0, 0, 0);
        }
    }
    #pragma unroll
    for (int mi = 0; mi < 4; ++mi) {
        #pragma unroll
        for (int nj = 0; nj < 4; ++nj) {
            #pragma unroll
            for (int r = 0; r < 4; ++r) {
                int gm = m0 + wm * 64 + mi * 16 + lg * 4 + r;
                int gn = n0 + wn * 64 + nj * 16 + lr;
                float v = acc[mi][nj][r] + bias[gn];
                if (!is_out) {
                    int bb = gm >> 11, s = gm & 2047, hh = gn >> 6, dd = gn & 63;
                    outQKV[(size_t)z * 3145728 +
                           ((((size_t)bb * NH + hh) * SEQ + s) * DH + dd)] = (_Float16)v;
                } else {
                    outF32[(size_t)gm * 768 + gn] = v;
                }
            }
        }
    }
}

// ---------------- flash attention: per (b, h, 64 q-rows) -----------------
// 4 waves; wave w owns q-rows [16w,16w+16). K-tile=64.
// Register-prefetch pipeline for K/V and position_bias; swizzled LDS.
__global__ __launch_bounds__(256) void attn_kernel(
    const _Float16* __restrict__ Qh, const _Float16* __restrict__ Kh,
    const _Float16* __restrict__ Vh, const float* __restrict__ pb,
    const float* __restrict__ mask, _Float16* __restrict__ ctx)
{
    __shared__ _Float16 Kl[64 * 64];       // [kt][d], XOR-swizzled (kt&7)<<4
    __shared__ _Float16 Vt[64 * 64];       // [d][kt], XOR-swizzled ((d&7)^((d>>3)&7))<<4
    __shared__ _Float16 Pl[4 * 16 * 64];   // per-wave [qrow][kt], XOR-swizzled
    const int tid = threadIdx.x, w = tid >> 6, lane = tid & 63;
    const int lr = lane & 15, lg = lane >> 4;
    // XCD-aware swizzle: all 32 q-blocks of one (b,h) land on one XCD.
    const int lin = blockIdx.x;
    const int xcd = lin & 7, idx = lin >> 3;
    const int bh = xcd * 3 + (idx >> 5);
    const int q0 = (idx & 31) << 6;
    const int h = bh % NH, b = bh / NH;
    const size_t headoff = ((size_t)b * NH + h) * SEQ * DH;
    const _Float16* Qp = Qh + headoff;
    const _Float16* Kp = Kh + headoff;
    const _Float16* Vp = Vh + headoff;
    const float L2E = 1.44269504f;

    // Q A-frags: row = lr within wave's 16 rows, k = kf*32 + lg*8 + j
    f16x8 qf[2];
    #pragma unroll
    for (int kf = 0; kf < 2; ++kf)
        qf[kf] = *reinterpret_cast<const f16x8*>(
            Qp + (size_t)(q0 + w * 16 + lr) * DH + kf * 32 + lg * 8);

    const float* pbr[4];
    #pragma unroll
    for (int r = 0; r < 4; ++r)
        pbr[r] = pb + (size_t)h * SEQ * SEQ + (size_t)(q0 + w * 16 + lg * 4 + r) * SEQ;
    const float* mrow = mask + (size_t)b * SEQ;

    f32x4 oacc[4] = {};
    float m_r[4], l_r[4];
    #pragma unroll
    for (int r = 0; r < 4; ++r) { m_r[r] = -3.0e38f; l_r[r] = 0.f; }
    char* Pw = (char*)Pl + w * 2048;

    const int c0 = tid, c1 = tid + 256;
    const int row0 = c0 >> 3, col0 = (c0 & 7) << 3;
    const int row1 = c1 >> 3, col1 = (c1 & 7) << 3;
    f16x8 kn[2], vn[2];

    // prologue: tile 0 into regs -> LDS; pb tile 0 into regs
    kn[0] = *reinterpret_cast<const f16x8*>(Kp + c0 * 8);
    kn[1] = *reinterpret_cast<const f16x8*>(Kp + c1 * 8);
    vn[0] = *reinterpret_cast<const f16x8*>(Vp + c0 * 8);
    vn[1] = *reinterpret_cast<const f16x8*>(Vp + c1 * 8);
    float pbc[4][4];
    #pragma unroll
    for (int cf = 0; cf < 4; ++cf) {
        float mk = mrow[cf * 16 + lr];
        #pragma unroll
        for (int r = 0; r < 4; ++r)
            pbc[cf][r] = (pbr[r][cf * 16 + lr] + mk) * L2E;
    }
    #pragma unroll
    for (int i = 0; i < 2; ++i) {
        int row = i ? row1 : row0, col = i ? col1 : col0;
        *reinterpret_cast<f16x8*>(
            (char*)Kl + ((row * 128 + col * 2) ^ ((row & 7) << 4))) = kn[i];
        #pragma unroll
        for (int j = 0; j < 8; ++j) {
            int d = col + j;
            *reinterpret_cast<_Float16*>(
                (char*)Vt + ((d * 128 + row * 2) ^ ((((d & 7) ^ ((d >> 3) & 7))) << 4))) = vn[i][j];
        }
    }
    __syncthreads();

    for (int kt0 = 0; kt0 < SEQ; kt0 += 64) {
        // ---- prefetch next tile into regs (hidden under compute) ----
        const int nt = (kt0 + 64 < SEQ) ? kt0 + 64 : kt0;
        kn[0] = *reinterpret_cast<const f16x8*>(Kp + (size_t)nt * DH + c0 * 8);
        kn[1] = *reinterpret_cast<const f16x8*>(Kp + (size_t)nt * DH + c1 * 8);
        vn[0] = *reinterpret_cast<const f16x8*>(Vp + (size_t)nt * DH + c0 * 8);
        vn[1] = *reinterpret_cast<const f16x8*>(Vp + (size_t)nt * DH + c1 * 8);
        float pbn[4][4];
        #pragma unroll
        for (int cf = 0; cf < 4; ++cf) {
            float mk = mrow[nt + cf * 16 + lr];
            #pragma unroll
            for (int r = 0; r < 4; ++r)
                pbn[cf][r] = (pbr[r][nt + cf * 16 + lr] + mk) * L2E;
        }

        // ---- QK^T on current tile ----
        f32x4 sc4[4] = {};
        #pragma unroll
        for (int cf = 0; cf < 4; ++cf) {
            #pragma unroll
            for (int kf = 0; kf < 2; ++kf) {
                f16x8 kb = *reinterpret_cast<const f16x8*>(
                    (char*)Kl + (((cf * 16 + lr) * 128 + kf * 64 + lg * 16) ^ ((lr & 7) << 4)));
                sc4[cf] = __builtin_amdgcn_mfma_f32_16x16x32_f16(qf[kf], kb, sc4[cf], 0, 0, 0);
            }
        }
        // scale (0.125 * log2e) + (pb + mask)*log2e, all in exp2 domain
        float sv[4][4];
        #pragma unroll
        for (int cf = 0; cf < 4; ++cf)
            #pragma unroll
            for (int r = 0; r < 4; ++r)
                sv[cf][r] = sc4[cf][r] * 0.18033688f + pbc[cf][r];

        // online softmax: rows live across 16 lanes (lr)
        float rs[4], scale[4];
        #pragma unroll
        for (int r = 0; r < 4; ++r) {
            float t = fmaxf(fmaxf(sv[0][r], sv[1][r]), fmaxf(sv[2][r], sv[3][r]));
            #pragma unroll
            for (int msk = 1; msk < 16; msk <<= 1) t = fmaxf(t, __shfl_xor(t, msk));
            float mn = fmaxf(m_r[r], t);
            scale[r] = exp2f(m_r[r] - mn);
            m_r[r] = mn;
            rs[r] = 0.f;
        }
        #pragma unroll
        for (int cf = 0; cf < 4; ++cf)
            #pragma unroll
            for (int r = 0; r < 4; ++r) {
                float p = exp2f(sv[cf][r] - m_r[r]);
                rs[r] += p;
                int prow = lg * 4 + r;
                *reinterpret_cast<_Float16*>(
                    Pw + ((prow * 128 + (cf * 16 + lr) * 2) ^ ((prow & 7) << 4))) = (_Float16)p;
            }
        #pragma unroll
        for (int r = 0; r < 4; ++r) {
            #pragma unroll
            for (int msk = 1; msk < 16; msk <<= 1) rs[r] += __shfl_xor(rs[r], msk);
            l_r[r] = l_r[r] * scale[r] + rs[r];
        }
        #pragma unroll
        for (int cf = 0; cf < 4; ++cf)
            #pragma unroll
            for (int r = 0; r < 4; ++r) oacc[cf][r] *= scale[r];

        // ---- PV on current tile ----
        #pragma unroll
        for (int kf = 0; kf < 2; ++kf) {
            f16x8 pa = *reinterpret_cast<const f16x8*>(
                Pw + ((lr * 128 + kf * 64 + lg * 16) ^ ((lr & 7) << 4)));
            #pragma unroll
            for (int cf = 0; cf < 4; ++cf) {
                int d = cf * 16 + lr;
                f16x8 vb = *reinterpret_cast<const f16x8*>(
                    (char*)Vt + ((d * 128 + kf * 64 + lg * 16) ^ ((((d & 7) ^ ((d >> 3) & 7))) << 4)));
                oacc[cf] = __builtin_amdgcn_mfma_f32_16x16x32_f16(pa, vb, oacc[cf], 0, 0, 0);
            }
        }

        // ---- commit prefetched tile ----
        __syncthreads();
        #pragma unroll
        for (int i = 0; i < 2; ++i) {
            int row = i ? row1 : row0, col = i ? col1 : col0;
            *reinterpret_cast<f16x8*>(
                (char*)Kl + ((row * 128 + col * 2) ^ ((row & 7) << 4))) = kn[i];
            #pragma unroll
            for (int j = 0; j < 8; ++j) {
                int d = col + j;
                *reinterpret_cast<_Float16*>(
                    (char*)Vt + ((d * 128 + row * 2) ^ ((((d & 7) ^ ((d >> 3) & 7))) << 4))) = vn[i][j];
            }
        }
        #pragma unroll
        for (int cf = 0; cf < 4; ++cf)
            #pragma unroll
            for (int r = 0; r < 4; ++r) pbc[cf][r] = pbn[cf][r];
        __syncthreads();
    }

    // epilogue: ctx[b, s, h*64+d] fp16
    #pragma unroll
    for (int r = 0; r < 4; ++r) {
        float inv = 1.0f / l_r[r];
        int grow = q0 + w * 16 + lg * 4 + r;
        #pragma unroll
        for (int cf = 0; cf < 4; ++cf)
            ctx[((size_t)b * SEQ + grow) * DM + h * DH + cf * 16 + lr] =
                (_Float16)(oacc[cf][r] * inv);
    }
}

extern "C" void kernel_launch(void* const* d_in, const int* in_sizes, int n_in,
                              void* d_out, int out_size, void* d_ws, size_t ws_size,
                              hipStream_t stream) {
    const float* X    = (const float*)d_in[0];
    const float* mask = (const float*)d_in[1];
    const float* pb   = (const float*)d_in[2];
    const float* Wq   = (const float*)d_in[3];
    const float* bq   = (const float*)d_in[4];
    const float* Wk   = (const float*)d_in[5];
    const float* bk   = (const float*)d_in[6];
    const float* Wv   = (const float*)d_in[7];
    const float* bv   = (const float*)d_in[8];
    const float* Wo   = (const float*)d_in[9];
    const float* bo   = (const float*)d_in[10];
    float* out = (float*)d_out;

    _Float16* Xh   = (_Float16*)d_ws;            // 3145728
    _Float16* Wall = Xh + 3145728;               // 4 * 589824 (q,k,v,o)
    _Float16* QKV  = Wall + 4 * 589824;          // 3 * 3145728
    _Float16* ctx  = QKV + 3 * 3145728;          // 3145728

    cast_kernel<<<2688, 256, 0, stream>>>(X, Wq, Wk, Wv, Wo, Xh, Wall);
    gemm_kernel<<<dim3(32, 6, 3), 256, 0, stream>>>(
        Xh, Wall, bq, bk, bv, QKV, nullptr, 0);
    attn_kernel<<<768, 256, 0, stream>>>(
        QKV, QKV + 3145728, QKV + 2 * 3145728, pb, mask, ctx);
    gemm_kernel<<<dim3(32, 6, 1), 256, 0, stream>>>(
        ctx, Wall + 3 * 589824, bo, bo, bo, nullptr, out, 1);
}

// Round 3
// 190.183 us; speedup vs baseline: 1.0503x; 1.0099x over previous
//
#include <hip/hip_runtime.h>

typedef _Float16 f16x8 __attribute__((ext_vector_type(8)));
typedef float f32x4 __attribute__((ext_vector_type(4)));

#define NH 12
#define SEQ 2048
#define DM 768
#define DH 64
#define NROWS 49152  // 2*NH*SEQ

// ---------------- cast fp32 -> fp16 (X and the 4 weight matrices) --------
__global__ __launch_bounds__(256) void cast_kernel(
    const float* __restrict__ X, const float* __restrict__ Wq,
    const float* __restrict__ Wk, const float* __restrict__ Wv,
    const float* __restrict__ Wo, _Float16* __restrict__ Xh,
    _Float16* __restrict__ Wall)
{
    size_t base = ((size_t)blockIdx.x * 256 + threadIdx.x) * 8;
    const size_t NX = 3145728, NW = 589824, TOT = NX + 4 * NW;
    if (base >= TOT) return;
    const float* src;
    _Float16* dst;
    if (base < NX) { src = X + base; dst = Xh + base; }
    else {
        size_t r = base - NX;
        int w = (int)(r / NW);
        size_t o = r - (size_t)w * NW;
        src = (w == 0 ? Wq : w == 1 ? Wk : w == 2 ? Wv : Wo) + o;
        dst = Wall + r;
    }
    float4 a = *reinterpret_cast<const float4*>(src);
    float4 b = *reinterpret_cast<const float4*>(src + 4);
    f16x8 h;
    h[0] = (_Float16)a.x; h[1] = (_Float16)a.y; h[2] = (_Float16)a.z; h[3] = (_Float16)a.w;
    h[4] = (_Float16)b.x; h[5] = (_Float16)b.y; h[6] = (_Float16)b.z; h[7] = (_Float16)b.w;
    *reinterpret_cast<f16x8*>(dst) = h;
}

// ---------------- GEMM: out = A[4096x768] @ W^T + bias ------------------
__global__ __launch_bounds__(256) void gemm_kernel(
    const _Float16* __restrict__ A,
    const _Float16* __restrict__ Wbase,
    const float* __restrict__ b0, const float* __restrict__ b1,
    const float* __restrict__ b2,
    _Float16* __restrict__ outQKV, float* __restrict__ outF32, int is_out)
{
    __shared__ _Float16 Asm[128 * 64];
    __shared__ _Float16 Bsm[128 * 64];
    const int tid = threadIdx.x;
    const int m0 = blockIdx.x * 128, n0 = blockIdx.y * 128, z = blockIdx.z;
    const _Float16* Wp = Wbase + (size_t)z * 589824;
    const float* bias = (z == 0) ? b0 : (z == 1 ? b1 : b2);
    const int w = tid >> 6, lane = tid & 63, lr = lane & 15, lg = lane >> 4;
    const int wm = w >> 1, wn = w & 1;

    f32x4 acc[4][4] = {};
    for (int kt = 0; kt < 12; ++kt) {
        __syncthreads();
        #pragma unroll
        for (int i = 0; i < 4; ++i) {
            int c = tid + i * 256;
            int row = c >> 3, col = (c & 7) * 8;
            int sw = (row & 7) << 4;
            f16x8 av = *reinterpret_cast<const f16x8*>(A + (size_t)(m0 + row) * 768 + kt * 64 + col);
            *reinterpret_cast<f16x8*>((char*)Asm + ((row * 128 + col * 2) ^ sw)) = av;
            f16x8 bv = *reinterpret_cast<const f16x8*>(Wp + (size_t)(n0 + row) * 768 + kt * 64 + col);
            *reinterpret_cast<f16x8*>((char*)Bsm + ((row * 128 + col * 2) ^ sw)) = bv;
        }
        __syncthreads();
        #pragma unroll
        for (int kf = 0; kf < 2; ++kf) {
            f16x8 af[4], bf[4];
            #pragma unroll
            for (int mi = 0; mi < 4; ++mi) {
                int row = wm * 64 + mi * 16 + lr;
                af[mi] = *reinterpret_cast<const f16x8*>(
                    (char*)Asm + ((row * 128 + kf * 64 + lg * 16) ^ ((row & 7) << 4)));
            }
            #pragma unroll
            for (int nj = 0; nj < 4; ++nj) {
                int row = wn * 64 + nj * 16 + lr;
                bf[nj] = *reinterpret_cast<const f16x8*>(
                    (char*)Bsm + ((row * 128 + kf * 64 + lg * 16) ^ ((row & 7) << 4)));
            }
            #pragma unroll
            for (int mi = 0; mi < 4; ++mi)
                #pragma unroll
                for (int nj = 0; nj < 4; ++nj)
                    acc[mi][nj] = __builtin_amdgcn_mfma_f32_16x16x32_f16(
                        af[mi], bf[nj], acc[mi][nj], 0, 0, 0);
        }
    }
    #pragma unroll
    for (int mi = 0; mi < 4; ++mi) {
        #pragma unroll
        for (int nj = 0; nj < 4; ++nj) {
            #pragma unroll
            for (int r = 0; r < 4; ++r) {
                int gm = m0 + wm * 64 + mi * 16 + lg * 4 + r;
                int gn = n0 + wn * 64 + nj * 16 + lr;
                float v = acc[mi][nj][r] + bias[gn];
                if (!is_out) {
                    int bb = gm >> 11, s = gm & 2047, hh = gn >> 6, dd = gn & 63;
                    outQKV[(size_t)z * 3145728 +
                           ((((size_t)bb * NH + hh) * SEQ + s) * DH + dd)] = (_Float16)v;
                } else {
                    outF32[(size_t)gm * 768 + gn] = v;
                }
            }
        }
    }
}

// ---------------- flash attention, 2-way split-K -------------------------
// Block = (b, h, 64 q-rows, ks half of K range). 4 waves; wave w owns
// q-rows [16w,16w+16). K-tile=64, 16 iterations. Writes unnormalized O
// (fp16) + per-row (m, l) in exp2 domain; merge_kernel combines.
__global__ __launch_bounds__(256) void attn_kernel(
    const _Float16* __restrict__ Qh, const _Float16* __restrict__ Kh,
    const _Float16* __restrict__ Vh, const float* __restrict__ pb,
    const float* __restrict__ mask, _Float16* __restrict__ Opart,
    float* __restrict__ ml)
{
    __shared__ _Float16 Kl[64 * 64];       // [kt][d], XOR-swizzled (kt&7)<<4
    __shared__ _Float16 Vt[64 * 64];       // [d][kt], XOR-swizzled ((d&7)^((d>>3)&7))<<4
    __shared__ _Float16 Pl[4 * 16 * 64];   // per-wave [qrow][kt], XOR-swizzled
    const int tid = threadIdx.x, w = tid >> 6, lane = tid & 63;
    const int lr = lane & 15, lg = lane >> 4;
    // XCD-aware decode: 1536 blocks = 8 XCD * (3 bh * 32 q0 * 2 ks)
    const int lin = blockIdx.x;
    const int xcd = lin & 7, idx = lin >> 3;       // idx in [0,192)
    const int bh = xcd * 3 + (idx >> 6);
    const int rem = idx & 63;
    const int q0 = (rem >> 1) << 6;
    const int ks = rem & 1;
    const int kbase = ks << 10;                    // ks*1024
    const int kend = kbase + 1024;
    const int h = bh % NH, b = bh / NH;
    const size_t headoff = ((size_t)b * NH + h) * SEQ * DH;
    const _Float16* Qp = Qh + headoff;
    const _Float16* Kp = Kh + headoff;
    const _Float16* Vp = Vh + headoff;
    const float L2E = 1.44269504f;

    f16x8 qf[2];
    #pragma unroll
    for (int kf = 0; kf < 2; ++kf)
        qf[kf] = *reinterpret_cast<const f16x8*>(
            Qp + (size_t)(q0 + w * 16 + lr) * DH + kf * 32 + lg * 8);

    const float* pbr[4];
    #pragma unroll
    for (int r = 0; r < 4; ++r)
        pbr[r] = pb + (size_t)h * SEQ * SEQ + (size_t)(q0 + w * 16 + lg * 4 + r) * SEQ;
    const float* mrow = mask + (size_t)b * SEQ;

    f32x4 oacc[4] = {};
    float m_r[4], l_r[4];
    #pragma unroll
    for (int r = 0; r < 4; ++r) { m_r[r] = -3.0e38f; l_r[r] = 0.f; }
    char* Pw = (char*)Pl + w * 2048;

    const int c0 = tid, c1 = tid + 256;
    const int row0 = c0 >> 3, col0 = (c0 & 7) << 3;
    const int row1 = c1 >> 3, col1 = (c1 & 7) << 3;
    f16x8 kn[2], vn[2];

    // prologue: first tile of this split into regs -> LDS; pb tile into regs
    kn[0] = *reinterpret_cast<const f16x8*>(Kp + (size_t)kbase * DH + c0 * 8);
    kn[1] = *reinterpret_cast<const f16x8*>(Kp + (size_t)kbase * DH + c1 * 8);
    vn[0] = *reinterpret_cast<const f16x8*>(Vp + (size_t)kbase * DH + c0 * 8);
    vn[1] = *reinterpret_cast<const f16x8*>(Vp + (size_t)kbase * DH + c1 * 8);
    float pbc[4][4];
    #pragma unroll
    for (int cf = 0; cf < 4; ++cf) {
        float mk = mrow[kbase + cf * 16 + lr];
        #pragma unroll
        for (int r = 0; r < 4; ++r)
            pbc[cf][r] = (pbr[r][kbase + cf * 16 + lr] + mk) * L2E;
    }
    #pragma unroll
    for (int i = 0; i < 2; ++i) {
        int row = i ? row1 : row0, col = i ? col1 : col0;
        *reinterpret_cast<f16x8*>(
            (char*)Kl + ((row * 128 + col * 2) ^ ((row & 7) << 4))) = kn[i];
        #pragma unroll
        for (int j = 0; j < 8; ++j) {
            int d = col + j;
            *reinterpret_cast<_Float16*>(
                (char*)Vt + ((d * 128 + row * 2) ^ ((((d & 7) ^ ((d >> 3) & 7))) << 4))) = vn[i][j];
        }
    }
    __syncthreads();

    for (int kt0 = kbase; kt0 < kend; kt0 += 64) {
        // ---- prefetch next tile into regs (hidden under compute) ----
        const int nt = (kt0 + 64 < kend) ? kt0 + 64 : kt0;
        kn[0] = *reinterpret_cast<const f16x8*>(Kp + (size_t)nt * DH + c0 * 8);
        kn[1] = *reinterpret_cast<const f16x8*>(Kp + (size_t)nt * DH + c1 * 8);
        vn[0] = *reinterpret_cast<const f16x8*>(Vp + (size_t)nt * DH + c0 * 8);
        vn[1] = *reinterpret_cast<const f16x8*>(Vp + (size_t)nt * DH + c1 * 8);
        float pbn[4][4];
        #pragma unroll
        for (int cf = 0; cf < 4; ++cf) {
            float mk = mrow[nt + cf * 16 + lr];
            #pragma unroll
            for (int r = 0; r < 4; ++r)
                pbn[cf][r] = (pbr[r][nt + cf * 16 + lr] + mk) * L2E;
        }

        // ---- QK^T on current tile ----
        f32x4 sc4[4] = {};
        #pragma unroll
        for (int cf = 0; cf < 4; ++cf) {
            #pragma unroll
            for (int kf = 0; kf < 2; ++kf) {
                f16x8 kb = *reinterpret_cast<const f16x8*>(
                    (char*)Kl + (((cf * 16 + lr) * 128 + kf * 64 + lg * 16) ^ ((lr & 7) << 4)));
                sc4[cf] = __builtin_amdgcn_mfma_f32_16x16x32_f16(qf[kf], kb, sc4[cf], 0, 0, 0);
            }
        }
        float sv[4][4];
        #pragma unroll
        for (int cf = 0; cf < 4; ++cf)
            #pragma unroll
            for (int r = 0; r < 4; ++r)
                sv[cf][r] = sc4[cf][r] * 0.18033688f + pbc[cf][r];

        // online softmax (exp2 domain): rows live across 16 lanes (lr)
        float rs[4], scale[4];
        #pragma unroll
        for (int r = 0; r < 4; ++r) {
            float t = fmaxf(fmaxf(sv[0][r], sv[1][r]), fmaxf(sv[2][r], sv[3][r]));
            #pragma unroll
            for (int msk = 1; msk < 16; msk <<= 1) t = fmaxf(t, __shfl_xor(t, msk));
            float mn = fmaxf(m_r[r], t);
            scale[r] = exp2f(m_r[r] - mn);
            m_r[r] = mn;
            rs[r] = 0.f;
        }
        #pragma unroll
        for (int cf = 0; cf < 4; ++cf)
            #pragma unroll
            for (int r = 0; r < 4; ++r) {
                float p = exp2f(sv[cf][r] - m_r[r]);
                rs[r] += p;
                int prow = lg * 4 + r;
                *reinterpret_cast<_Float16*>(
                    Pw + ((prow * 128 + (cf * 16 + lr) * 2) ^ ((prow & 7) << 4))) = (_Float16)p;
            }
        #pragma unroll
        for (int r = 0; r < 4; ++r) {
            #pragma unroll
            for (int msk = 1; msk < 16; msk <<= 1) rs[r] += __shfl_xor(rs[r], msk);
            l_r[r] = l_r[r] * scale[r] + rs[r];
        }
        #pragma unroll
        for (int cf = 0; cf < 4; ++cf)
            #pragma unroll
            for (int r = 0; r < 4; ++r) oacc[cf][r] *= scale[r];

        // ---- PV on current tile ----
        #pragma unroll
        for (int kf = 0; kf < 2; ++kf) {
            f16x8 pa = *reinterpret_cast<const f16x8*>(
                Pw + ((lr * 128 + kf * 64 + lg * 16) ^ ((lr & 7) << 4)));
            #pragma unroll
            for (int cf = 0; cf < 4; ++cf) {
                int d = cf * 16 + lr;
                f16x8 vb = *reinterpret_cast<const f16x8*>(
                    (char*)Vt + ((d * 128 + kf * 64 + lg * 16) ^ ((((d & 7) ^ ((d >> 3) & 7))) << 4)));
                oacc[cf] = __builtin_amdgcn_mfma_f32_16x16x32_f16(pa, vb, oacc[cf], 0, 0, 0);
            }
        }

        // ---- commit prefetched tile ----
        __syncthreads();
        #pragma unroll
        for (int i = 0; i < 2; ++i) {
            int row = i ? row1 : row0, col = i ? col1 : col0;
            *reinterpret_cast<f16x8*>(
                (char*)Kl + ((row * 128 + col * 2) ^ ((row & 7) << 4))) = kn[i];
            #pragma unroll
            for (int j = 0; j < 8; ++j) {
                int d = col + j;
                *reinterpret_cast<_Float16*>(
                    (char*)Vt + ((d * 128 + row * 2) ^ ((((d & 7) ^ ((d >> 3) & 7))) << 4))) = vn[i][j];
            }
        }
        #pragma unroll
        for (int cf = 0; cf < 4; ++cf)
            #pragma unroll
            for (int r = 0; r < 4; ++r) pbc[cf][r] = pbn[cf][r];
        __syncthreads();
    }

    // epilogue: unnormalized O (fp16) + (m,l) per row
    #pragma unroll
    for (int r = 0; r < 4; ++r) {
        int grow = q0 + w * 16 + lg * 4 + r;
        size_t rowi = ((size_t)b * NH + h) * SEQ + grow;
        _Float16* od = Opart + ((size_t)ks * NROWS + rowi) * DH;
        #pragma unroll
        for (int cf = 0; cf < 4; ++cf)
            od[cf * 16 + lr] = (_Float16)oacc[cf][r];
        if (lr == 0) {
            ml[rowi * 4 + ks * 2 + 0] = m_r[r];
            ml[rowi * 4 + ks * 2 + 1] = l_r[r];
        }
    }
}

// ---------------- merge the two split-K partials -------------------------
__global__ __launch_bounds__(256) void merge_kernel(
    const _Float16* __restrict__ Opart, const float* __restrict__ ml,
    _Float16* __restrict__ ctx)
{
    int gid = blockIdx.x * 256 + threadIdx.x;      // 49152*8 threads
    int row = gid >> 3, d8 = (gid & 7) << 3;
    const size_t NP = (size_t)NROWS * DH;
    f16x8 o0 = *reinterpret_cast<const f16x8*>(Opart + (size_t)row * DH + d8);
    f16x8 o1 = *reinterpret_cast<const f16x8*>(Opart + NP + (size_t)row * DH + d8);
    float4 m = *reinterpret_cast<const float4*>(ml + (size_t)row * 4);
    float M = fmaxf(m.x, m.z);
    float a0 = exp2f(m.x - M), a1 = exp2f(m.z - M);
    float inv = 1.0f / (a0 * m.y + a1 * m.w);
    a0 *= inv; a1 *= inv;
    f16x8 o;
    #pragma unroll
    for (int j = 0; j < 8; ++j)
        o[j] = (_Float16)(a0 * (float)o0[j] + a1 * (float)o1[j]);
    int b = row / (NH * SEQ);
    int hs = row - b * (NH * SEQ);
    int h = hs >> 11, s = hs & 2047;
    *reinterpret_cast<f16x8*>(ctx + ((size_t)b * SEQ + s) * DM + h * DH + d8) = o;
}

extern "C" void kernel_launch(void* const* d_in, const int* in_sizes, int n_in,
                              void* d_out, int out_size, void* d_ws, size_t ws_size,
                              hipStream_t stream) {
    const float* X    = (const float*)d_in[0];
    const float* mask = (const float*)d_in[1];
    const float* pb   = (const float*)d_in[2];
    const float* Wq   = (const float*)d_in[3];
    const float* bq   = (const float*)d_in[4];
    const float* Wk   = (const float*)d_in[5];
    const float* bk   = (const float*)d_in[6];
    const float* Wv   = (const float*)d_in[7];
    const float* bv   = (const float*)d_in[8];
    const float* Wo   = (const float*)d_in[9];
    const float* bo   = (const float*)d_in[10];
    float* out = (float*)d_out;

    _Float16* Xh    = (_Float16*)d_ws;            // 3145728 f16
    _Float16* Wall  = Xh + 3145728;               // 4 * 589824 f16
    _Float16* QKV   = Wall + 4 * 589824;          // 3 * 3145728 f16
    _Float16* ctx   = QKV + 3 * 3145728;          // 3145728 f16
    _Float16* Opart = ctx + 3145728;              // 2 * 3145728 f16
    float*    ml    = (float*)(Opart + 2 * 3145728); // 49152*4 f32

    cast_kernel<<<2688, 256, 0, stream>>>(X, Wq, Wk, Wv, Wo, Xh, Wall);
    gemm_kernel<<<dim3(32, 6, 3), 256, 0, stream>>>(
        Xh, Wall, bq, bk, bv, QKV, nullptr, 0);
    attn_kernel<<<1536, 256, 0, stream>>>(
        QKV, QKV + 3145728, QKV + 2 * 3145728, pb, mask, Opart, ml);
    merge_kernel<<<1536, 256, 0, stream>>>(Opart, ml, ctx);
    gemm_kernel<<<dim3(32, 6, 1), 256, 0, stream>>>(
        ctx, Wall + 3 * 589824, bo, bo, bo, nullptr, out, 1);
}